// Round 24
// baseline (45.766 us; speedup 1.0000x reference)
//
#include <hip/hip_runtime.h>
#include <hip/hip_bf16.h>
#include <stdint.h>

#define S_SCALE 30.0f
#define XSC 360.0f                 /* A int8 scale (max|xn| ~ 0.39 w/ clamp) */
#define WSC 400.0f                 /* W int8 scale (max|W| ~ 0.26) */
#define SC_EPI 3.00561467e-4f      /* 30*log2(e) / (360*400) */
#define N_ROWS 8192
#define D_DIM 256
#define C_CLS 10000
#define NCB 16

typedef __attribute__((ext_vector_type(4))) int i32x4;

static __device__ __forceinline__ void gl16(const void* g, void* l) {
  __builtin_amdgcn_global_load_lds(
      (const __attribute__((address_space(1))) void*)g,
      (__attribute__((address_space(3))) void*)l, 16, 0, 0);
}

// quantize 4 floats (pre-scaled) to packed int8x4, clamp +-127, round-nearest
static __device__ __forceinline__ int q4(float a, float b, float c, float d) {
  int qa = (int)rintf(fminf(fmaxf(a, -127.f), 127.f));
  int qb = (int)rintf(fminf(fmaxf(b, -127.f), 127.f));
  int qc = (int)rintf(fminf(fmaxf(c, -127.f), 127.f));
  int qd = (int)rintf(fminf(fmaxf(d, -127.f), 127.f));
  return (qa & 255) | ((qb & 255) << 8) | ((qc & 255) << 16) | ((qd & 255) << 24);
}

// 16-lane (DPP-row) sum, VALU pipe only; all lanes receive the group sum.
static __device__ __forceinline__ float row_sum16(float v) {
  union { float f; int i; } u, w;
  u.f = v;
  w.i = __builtin_amdgcn_update_dpp(0, u.i, 0xB1, 0xF, 0xF, true);  u.f += w.f; // lane^1
  w.i = __builtin_amdgcn_update_dpp(0, u.i, 0x4E, 0xF, 0xF, true);  u.f += w.f; // lane^2
  w.i = __builtin_amdgcn_update_dpp(0, u.i, 0x141, 0xF, 0xF, true); u.f += w.f; // half-mirror
  w.i = __builtin_amdgcn_update_dpp(0, u.i, 0x140, 0xF, 0xF, true); u.f += w.f; // row-mirror
  return u.f;
}

// ---- fused prep (int8) -- VERBATIM from r23 (absmax 0.0 verified) ----
// WbF8: [c16 0..639][kchunk 0..3][lane]16B; lane=lk*16+lr holds
// W[col=c16*16+lr][k=kchunk*64+lk*16 ..+16] as int8; cols >= C_CLS zero
// (acc contribution 0 -> exp2(0)=1, subtracted in k_loss1).
// xnb8: [panel 0..63] 32KB: slot (r16*4+kchunk)*1024 + flane*16 + byte;
// row = panel*128 + r16*16 + lr, flane = lk*16+lr, k = kchunk*64+lk*16+byte.
__global__ __launch_bounds__(256) void k_prep(const float* __restrict__ x,
                                              const float* __restrict__ W,
                                              const int* __restrict__ target,
                                              unsigned char* __restrict__ xnb8,
                                              unsigned char* __restrict__ WbF8,
                                              float* __restrict__ tgt) {
  if (blockIdx.x < 1280) {
    int gidx = blockIdx.x * 256 + threadIdx.x;   // 0..327679 = 640*4*64*2
    int sub = gidx & 1;                          // which 8B half of lane's 16B
    int lane = (gidx >> 1) & 63;
    int kchunk = (gidx >> 7) & 3;
    int c16 = gidx >> 9;
    int col = c16 * 16 + (lane & 15);
    int k0 = kchunk * 64 + (lane >> 4) * 16 + sub * 8;
    int r0 = 0, r1 = 0;
    if (col < C_CLS) {
      const float4 a = *(const float4*)(W + (size_t)col * D_DIM + k0);
      const float4 b = *(const float4*)(W + (size_t)col * D_DIM + k0 + 4);
      r0 = q4(a.x * WSC, a.y * WSC, a.z * WSC, a.w * WSC);
      r1 = q4(b.x * WSC, b.y * WSC, b.z * WSC, b.w * WSC);
    }
    size_t dst = (size_t)c16 * 4096 + (size_t)kchunk * 1024 +
                 (size_t)lane * 16 + (size_t)sub * 8;
    *(int2*)(WbF8 + dst) = (int2){r0, r1};
  } else {
    int row = (blockIdx.x - 1280) * 4 + (threadIdx.x >> 6);
    int l = threadIdx.x & 63;
    const float4 v = *(const float4*)(x + (size_t)row * D_DIM + l * 4);
    float ss = v.x * v.x + v.y * v.y + v.z * v.z + v.w * v.w;
#pragma unroll
    for (int m = 1; m < 64; m <<= 1) ss += __shfl_xor(ss, m, 64);
    float rn = 1.0f / sqrtf(ss);
    float s8 = rn * XSC;
    int r0 = q4(v.x * s8, v.y * s8, v.z * s8, v.w * s8);
    // this thread's 4 k-bytes: k0 = l*4
    int panel = row >> 7, r16 = (row >> 4) & 7, lr = row & 15;
    int kchunk = l >> 4;
    int lk = (l >> 2) & 3;
    int byte = (l & 3) * 4;
    size_t dst = (size_t)panel * 32768 + (size_t)(r16 * 4 + kchunk) * 1024 +
                 (size_t)(lk * 16 + lr) * 16 + byte;
    *(int*)(xnb8 + dst) = r0;
    // exact fp32 target logit
    int tc = target[row];
    const float4 b = *(const float4*)(W + (size_t)tc * D_DIM + l * 4);
    float s = v.x * b.x + v.y * b.y + v.z * b.z + v.w * b.w;
#pragma unroll
    for (int m = 1; m < 64; m <<= 1) s += __shfl_xor(s, m, 64);
    if (l == 0) tgt[row] = s * rn;
  }
}

// ------- barrier-free fused i8 GEMM (16x16x64) + exp-sum, DEPTH-2 B PREFETCH ----
// 1024 blocks (64 br x 8 cg x 2 sub), 256 thr = 4 waves (2wr x 2wc), wave tile
// 64x64, block tile 128x128, 5 tiles of 128 cols. launch_bounds(256,3): 168-reg
// cap fits acc(64 AGPR) + FOUR B buffers (64 VGPR) + A 4 + addr ~ 152 -> no
// spill, 3 blocks/CU = 12 waves/CU. i8 halved the per-window MFMA work
// (82 cyc vs fp8's 310) so r23's unprefetched B-L2 latency (~400-600 cyc)
// dominates (est MfmaUtil ~9%). Fix: 4-buffer period-4 rotation = depth-2
// prefetch with fully static register names: w0:P(pre w2->R), w1:Q(pre w3->S),
// w2:R(pre nextT w0->P), w3:S(pre nextT w1->Q) -- tile boundary covered under
// the epilogue VALU. int32 acc exact; layouts verbatim r23 (absmax 0.0).
__global__ __launch_bounds__(256, 3) void k_gemm(const unsigned char* __restrict__ xnb8,
                                                 const unsigned char* __restrict__ WbF8,
                                                 float* __restrict__ partials) {
  __shared__ __align__(16) char lds[33792];   // A frags 32 KB @0; rsum 1 KB @32768
  const int b = blockIdx.x;
  const int cg = b & 7;                        // XCD colgroup
  const int sub = (b >> 3) & 1;                // 640-col half
  const int br = b >> 4;                       // row panel 0..63 (128 rows)
  const int t = threadIdx.x;
  const int w = t >> 6, l = t & 63;
  const int wr = w >> 1, wc = w & 1;           // 2M x 2N waves (64x64 tile)
  const int lr = l & 15, lk = l >> 4;
  float* rsumAll = (float*)(lds + 32768);      // [4 waves][64 rows]

  rsumAll[t] = 0.f;                            // covered by staging barrier

  // ---- stage A panel once: pure linear 32 KB copy into frag-order LDS ----
  {
    const char* Ag = (const char*)xnb8 + (size_t)br * 32768;
#pragma unroll
    for (int i = 0; i < 8; ++i)
      gl16(Ag + i * 4096 + w * 1024 + l * 16, lds + i * 4096 + w * 1024);
    asm volatile("s_waitcnt vmcnt(0)" ::: "memory");
    __builtin_amdgcn_sched_barrier(0);
    __builtin_amdgcn_s_barrier();
  }

  i32x4 acc[4][4];
  const i32x4 zi = (i32x4){0, 0, 0, 0};

  // wave's A base in LDS (slot = (wr*4+fm)*4 + kc, 1024 B each), per-lane 16B
  const char* AwL = lds + (size_t)wr * 16384 + (size_t)l * 16;
  // wave's B base: c16 = (cg*2+sub)*40 + tt*8 + wc*4 + fn; c16 stride 4096
  const unsigned char* Bw = WbF8 + (size_t)((cg * 2 + sub) * 40 + wc * 4) * 4096 +
                            (size_t)l * 16;
  float* rw = rsumAll + w * 64;                // this wave's private rows

  // 4 static B buffers, period-4 rotation = depth-2 prefetch
  i32x4 P[4], Q[4], R[4], S[4];
#pragma unroll
  for (int fn = 0; fn < 4; ++fn) {
    P[fn] = *(const i32x4*)(Bw + fn * 4096);           // tile0 w0
    Q[fn] = *(const i32x4*)(Bw + fn * 4096 + 1024);    // tile0 w1
  }

  for (int tt = 0; tt < 5; ++tt) {
    const unsigned char* Bt = Bw + (size_t)tt * 32768;   // 8 c16 per 128-col tile
    const bool nx = (tt < 4);

    auto windw = [&](int kc, bool first, i32x4(&cur)[4], i32x4(&pre)[4],
                     int preOff, bool doPre) {
      if (doPre) {
#pragma unroll
        for (int fn = 0; fn < 4; ++fn)
          pre[fn] = *(const i32x4*)(Bt + fn * 4096 + preOff);
      }
      __builtin_amdgcn_s_setprio(1);
#pragma unroll
      for (int fm = 0; fm < 4; ++fm) {
        i32x4 a = *(const i32x4*)(AwL + (fm * 4 + kc) * 1024);
#pragma unroll
        for (int fn = 0; fn < 4; ++fn)
          acc[fm][fn] = __builtin_amdgcn_mfma_i32_16x16x64_i8(
              a, cur[fn], first ? zi : acc[fm][fn], 0, 0, 0);
      }
      __builtin_amdgcn_s_setprio(0);
    };
    windw(0, true,  P, R, 2 * 1024, true);           // pre w2 -> R
    windw(1, false, Q, S, 3 * 1024, true);           // pre w3 -> S
    windw(2, false, R, P, 32768 + 0, nx);            // pre next-tile w0 -> P
    windw(3, false, S, Q, 32768 + 1024, nx);         // pre next-tile w1 -> Q

    // ---- per-tile epilogue: cvt+scale+exp2, DPP col-reduce, LDS rows ----
    // 16x16 C/D: col = lane&15, row = (lane>>4)*4 + j. No mask: padded cols
    // give acc=0 -> exp2(0)=1, removed as a constant in k_loss1.
#pragma unroll
    for (int m = 0; m < 4; ++m) {
      float rs0 = 0.f, rs1 = 0.f, rs2 = 0.f, rs3 = 0.f;
#pragma unroll
      for (int n = 0; n < 4; ++n) {
        rs0 += __builtin_amdgcn_exp2f((float)acc[m][n][0] * SC_EPI);
        rs1 += __builtin_amdgcn_exp2f((float)acc[m][n][1] * SC_EPI);
        rs2 += __builtin_amdgcn_exp2f((float)acc[m][n][2] * SC_EPI);
        rs3 += __builtin_amdgcn_exp2f((float)acc[m][n][3] * SC_EPI);
      }
      rs0 = row_sum16(rs0); rs1 = row_sum16(rs1);
      rs2 = row_sum16(rs2); rs3 = row_sum16(rs3);
      if (lr == 0) {
        int row = m * 16 + lk * 4;
        rw[row + 0] += rs0; rw[row + 1] += rs1;
        rw[row + 2] += rs2; rw[row + 3] += rs3;
      }
    }
  }

  // ---- final: combine 2 wc-waves per row, one coalesced store ----
  __syncthreads();
  if (t < 128) {
    int wr2 = t >> 6, r = t & 63;
    float sv = rsumAll[(wr2 * 2 + 0) * 64 + r] + rsumAll[(wr2 * 2 + 1) * 64 + r];
    partials[(size_t)(cg * 2 + sub) * N_ROWS + (size_t)br * 128 + t] = sv;
  }
}

// ---------------- per-row loss + block partial sums ----------------
__global__ __launch_bounds__(256) void k_loss1(const float* __restrict__ partials,
                                               const float* __restrict__ tgt,
                                               float* __restrict__ bsum) {
  __shared__ float wsum[4];
  int i = blockIdx.x * 256 + threadIdx.x;
  const float* p = partials + i;
  float s = -240.0f;   // remove padded cols 10000..10239 (acc=0 -> exp term 1.0)
#pragma unroll
  for (int j = 0; j < NCB; ++j) s += p[(size_t)j * N_ROWS];
  float tl = tgt[i];
  float tcv = fminf(fmaxf(tl, -1.0f + 1e-7f), 1.0f - 1e-7f);
  const float cm = 0.95533648912560601964f;   // cos(0.3)
  const float sm = 0.29552020666133957510f;   // sin(0.3)
  float num = S_SCALE * (tcv * cm - sqrtf(fmaxf(1.0f - tcv * tcv, 0.f)) * sm);
  float sum_excl = s - __expf(S_SCALE * tl);
  float denom = __expf(num) + sum_excl;
  float L = num - __logf(denom);
#pragma unroll
  for (int m = 1; m < 64; m <<= 1) L += __shfl_xor(L, m, 64);
  int l = threadIdx.x & 63, w = threadIdx.x >> 6;
  if (l == 0) wsum[w] = L;
  __syncthreads();
  if (threadIdx.x == 0) bsum[blockIdx.x] = wsum[0] + wsum[1] + wsum[2] + wsum[3];
}

__global__ void k_loss2(const float* __restrict__ bsum, float* __restrict__ out) {
  float s = 0.f;
  for (int i = 0; i < 32; ++i) s += bsum[i];
  out[0] = -s / (float)N_ROWS;
}

// ---------------- launch ----------------
extern "C" void kernel_launch(void* const* d_in, const int* in_sizes, int n_in,
                              void* d_out, int out_size, void* d_ws, size_t ws_size,
                              hipStream_t stream) {
  const float* x = (const float*)d_in[0];
  const float* W = (const float*)d_in[1];
  const int* target = (const int*)d_in[2];
  float* out = (float*)d_out;
  char* ws = (char*)d_ws;

  unsigned char* xnb8 = (unsigned char*)(ws);               // 64*32768     = 2,097,152
  unsigned char* WbF8 = (unsigned char*)(ws + 2097152);     // 640*4096     = 2,621,440
  float* tgt = (float*)(ws + 4718592);                      // 8192*4
  float* partials = (float*)(ws + 4751360);                 // 16*8192*4    = 524,288
  float* bsum = (float*)(ws + 5275648);                     // 32*4

  k_prep<<<3328, 256, 0, stream>>>(x, W, target, xnb8, WbF8, tgt);
  k_gemm<<<1024, 256, 0, stream>>>(xnb8, WbF8, partials);
  k_loss1<<<32, 256, 0, stream>>>(partials, tgt, bsum);
  k_loss2<<<1, 1, 0, stream>>>(bsum, out);
}

// Round 25
// 44.670 us; speedup vs baseline: 1.0245x; 1.0245x over previous
//
#include <hip/hip_runtime.h>
#include <hip/hip_bf16.h>
#include <stdint.h>

#define S_SCALE 30.0f
#define XSC 360.0f                 /* A int8 scale (max|xn| ~ 0.39 w/ clamp) */
#define WSC 400.0f                 /* W int8 scale (max|W| ~ 0.26) */
#define SC_EPI 3.00561467e-4f      /* 30*log2(e) / (360*400) */
#define N_ROWS 8192
#define D_DIM 256
#define C_CLS 10000
#define NCB 16

typedef __attribute__((ext_vector_type(4))) int i32x4;

static __device__ __forceinline__ void gl16(const void* g, void* l) {
  __builtin_amdgcn_global_load_lds(
      (const __attribute__((address_space(1))) void*)g,
      (__attribute__((address_space(3))) void*)l, 16, 0, 0);
}

// quantize 4 floats (pre-scaled) to packed int8x4, clamp +-127, round-nearest
static __device__ __forceinline__ int q4(float a, float b, float c, float d) {
  int qa = (int)rintf(fminf(fmaxf(a, -127.f), 127.f));
  int qb = (int)rintf(fminf(fmaxf(b, -127.f), 127.f));
  int qc = (int)rintf(fminf(fmaxf(c, -127.f), 127.f));
  int qd = (int)rintf(fminf(fmaxf(d, -127.f), 127.f));
  return (qa & 255) | ((qb & 255) << 8) | ((qc & 255) << 16) | ((qd & 255) << 24);
}

// 16-lane (DPP-row) sum, VALU pipe only; all lanes receive the group sum.
static __device__ __forceinline__ float row_sum16(float v) {
  union { float f; int i; } u, w;
  u.f = v;
  w.i = __builtin_amdgcn_update_dpp(0, u.i, 0xB1, 0xF, 0xF, true);  u.f += w.f; // lane^1
  w.i = __builtin_amdgcn_update_dpp(0, u.i, 0x4E, 0xF, 0xF, true);  u.f += w.f; // lane^2
  w.i = __builtin_amdgcn_update_dpp(0, u.i, 0x141, 0xF, 0xF, true); u.f += w.f; // half-mirror
  w.i = __builtin_amdgcn_update_dpp(0, u.i, 0x140, 0xF, 0xF, true); u.f += w.f; // row-mirror
  return u.f;
}

// ---- fused prep (int8) -- VERBATIM from r23 (absmax 0.0 verified) ----
// WbF8: [c16 0..639][kchunk 0..3][lane]16B; lane=lk*16+lr holds
// W[col=c16*16+lr][k=kchunk*64+lk*16 ..+16] as int8; cols >= C_CLS zero
// (acc contribution 0 -> exp2(0)=1, subtracted in k_loss1).
// xnb8: [panel 0..63] 32KB: slot (r16*4+kchunk)*1024 + flane*16 + byte;
// row = panel*128 + r16*16 + lr, flane = lk*16+lr, k = kchunk*64+lk*16+byte.
__global__ __launch_bounds__(256) void k_prep(const float* __restrict__ x,
                                              const float* __restrict__ W,
                                              const int* __restrict__ target,
                                              unsigned char* __restrict__ xnb8,
                                              unsigned char* __restrict__ WbF8,
                                              float* __restrict__ tgt) {
  if (blockIdx.x < 1280) {
    int gidx = blockIdx.x * 256 + threadIdx.x;   // 0..327679 = 640*4*64*2
    int sub = gidx & 1;                          // which 8B half of lane's 16B
    int lane = (gidx >> 1) & 63;
    int kchunk = (gidx >> 7) & 3;
    int c16 = gidx >> 9;
    int col = c16 * 16 + (lane & 15);
    int k0 = kchunk * 64 + (lane >> 4) * 16 + sub * 8;
    int r0 = 0, r1 = 0;
    if (col < C_CLS) {
      const float4 a = *(const float4*)(W + (size_t)col * D_DIM + k0);
      const float4 b = *(const float4*)(W + (size_t)col * D_DIM + k0 + 4);
      r0 = q4(a.x * WSC, a.y * WSC, a.z * WSC, a.w * WSC);
      r1 = q4(b.x * WSC, b.y * WSC, b.z * WSC, b.w * WSC);
    }
    size_t dst = (size_t)c16 * 4096 + (size_t)kchunk * 1024 +
                 (size_t)lane * 16 + (size_t)sub * 8;
    *(int2*)(WbF8 + dst) = (int2){r0, r1};
  } else {
    int row = (blockIdx.x - 1280) * 4 + (threadIdx.x >> 6);
    int l = threadIdx.x & 63;
    const float4 v = *(const float4*)(x + (size_t)row * D_DIM + l * 4);
    float ss = v.x * v.x + v.y * v.y + v.z * v.z + v.w * v.w;
#pragma unroll
    for (int m = 1; m < 64; m <<= 1) ss += __shfl_xor(ss, m, 64);
    float rn = 1.0f / sqrtf(ss);
    float s8 = rn * XSC;
    int r0 = q4(v.x * s8, v.y * s8, v.z * s8, v.w * s8);
    // this thread's 4 k-bytes: k0 = l*4
    int panel = row >> 7, r16 = (row >> 4) & 7, lr = row & 15;
    int kchunk = l >> 4;
    int lk = (l >> 2) & 3;
    int byte = (l & 3) * 4;
    size_t dst = (size_t)panel * 32768 + (size_t)(r16 * 4 + kchunk) * 1024 +
                 (size_t)(lk * 16 + lr) * 16 + byte;
    *(int*)(xnb8 + dst) = r0;
    // exact fp32 target logit
    int tc = target[row];
    const float4 b = *(const float4*)(W + (size_t)tc * D_DIM + l * 4);
    float s = v.x * b.x + v.y * b.y + v.z * b.z + v.w * b.w;
#pragma unroll
    for (int m = 1; m < 64; m <<= 1) s += __shfl_xor(s, m, 64);
    if (l == 0) tgt[row] = s * rn;
  }
}

// ------- barrier-free fused i8 GEMM (16x16x64) + exp-sum, A-IN-REGISTERS ----
// 1024 blocks (64 br x 8 cg x 2 sub), 256 thr = 4 waves (2wr x 2wc), wave tile
// 64x64, block tile 128x128, 5 tiles of 128 cols. __launch_bounds__(256,2):
// 256-reg cap fits acc(64 AGPR) + A-FRAGS IN REGS (16 frags x 4 = 64 VGPR,
// loaded ONCE -- A is reused by all 5 tiles, r23 re-read it from LDS 80x/wave
// with ~120cyc LDS latency on every window's critical path) + B P/Q double
// buffer (32) + addr ~ 175 regs, no spill. Windows are now 4 B-loads + 16 MFMA,
// ZERO LDS ops. 2 blocks/CU = 8 waves/CU; B prefetched 1 window (~326cyc MFMA)
// ahead >= L2 latency. int32 acc exact; layouts verbatim r23 (absmax 0.0).
__global__ __launch_bounds__(256, 2) void k_gemm(const unsigned char* __restrict__ xnb8,
                                                 const unsigned char* __restrict__ WbF8,
                                                 float* __restrict__ partials) {
  __shared__ __align__(16) char lds[33792];   // A stage 32 KB @0; rsum 1 KB @32768
  const int b = blockIdx.x;
  const int cg = b & 7;                        // XCD colgroup
  const int sub = (b >> 3) & 1;                // 640-col half
  const int br = b >> 4;                       // row panel 0..63 (128 rows)
  const int t = threadIdx.x;
  const int w = t >> 6, l = t & 63;
  const int wr = w >> 1, wc = w & 1;           // 2M x 2N waves (64x64 tile)
  const int lr = l & 15, lk = l >> 4;
  float* rsumAll = (float*)(lds + 32768);      // [4 waves][64 rows]

  rsumAll[t] = 0.f;                            // covered by staging barrier

  // ---- stage A panel once, then hoist this wave's 16 frags into registers ----
  {
    const char* Ag = (const char*)xnb8 + (size_t)br * 32768;
#pragma unroll
    for (int i = 0; i < 8; ++i)
      gl16(Ag + i * 4096 + w * 1024 + l * 16, lds + i * 4096 + w * 1024);
    asm volatile("s_waitcnt vmcnt(0)" ::: "memory");
    __builtin_amdgcn_sched_barrier(0);
    __builtin_amdgcn_s_barrier();
  }
  i32x4 afr[4][4];                             // [fm][kc], static indices only
  {
    const char* AwL = lds + (size_t)wr * 16384 + (size_t)l * 16;
#pragma unroll
    for (int fm = 0; fm < 4; ++fm)
#pragma unroll
      for (int kc = 0; kc < 4; ++kc)
        afr[fm][kc] = *(const i32x4*)(AwL + (fm * 4 + kc) * 1024);
  }

  i32x4 acc[4][4];
  const i32x4 zi = (i32x4){0, 0, 0, 0};

  // wave's B base: c16 = (cg*2+sub)*40 + tt*8 + wc*4 + fn; c16 stride 4096
  const unsigned char* Bw = WbF8 + (size_t)((cg * 2 + sub) * 40 + wc * 4) * 4096 +
                            (size_t)l * 16;
  float* rw = rsumAll + w * 64;                // this wave's private rows

  // B double-buffer P/Q (period-2 over the 4 windows/tile)
  i32x4 P[4], Q[4];
#pragma unroll
  for (int fn = 0; fn < 4; ++fn) P[fn] = *(const i32x4*)(Bw + fn * 4096);

  for (int tt = 0; tt < 5; ++tt) {
    const unsigned char* Bt = Bw + (size_t)tt * 32768;   // 8 c16 per 128-col tile
    const bool nx = (tt < 4);

    auto windw = [&](int kc, bool first, i32x4(&cur)[4], i32x4(&pre)[4],
                     int preOff, bool doPre) {
      if (doPre) {
#pragma unroll
        for (int fn = 0; fn < 4; ++fn)
          pre[fn] = *(const i32x4*)(Bt + fn * 4096 + preOff);
      }
      __builtin_amdgcn_s_setprio(1);
#pragma unroll
      for (int fm = 0; fm < 4; ++fm) {
#pragma unroll
        for (int fn = 0; fn < 4; ++fn)
          acc[fm][fn] = __builtin_amdgcn_mfma_i32_16x16x64_i8(
              afr[fm][kc], cur[fn], first ? zi : acc[fm][fn], 0, 0, 0);
      }
      __builtin_amdgcn_s_setprio(0);
    };
    windw(0, true,  P, Q, 1 * 1024, true);       // pre w1 -> Q
    windw(1, false, Q, P, 2 * 1024, true);       // pre w2 -> P
    windw(2, false, P, Q, 3 * 1024, true);       // pre w3 -> Q
    windw(3, false, Q, P, 32768 + 0, nx);        // pre next-tile w0 -> P

    // ---- per-tile epilogue: cvt+scale+exp2, DPP col-reduce, LDS rows ----
    // 16x16 C/D: col = lane&15, row = (lane>>4)*4 + j. No mask: padded cols
    // give acc=0 -> exp2(0)=1, removed as a constant in k_loss1.
#pragma unroll
    for (int m = 0; m < 4; ++m) {
      float rs0 = 0.f, rs1 = 0.f, rs2 = 0.f, rs3 = 0.f;
#pragma unroll
      for (int n = 0; n < 4; ++n) {
        rs0 += __builtin_amdgcn_exp2f((float)acc[m][n][0] * SC_EPI);
        rs1 += __builtin_amdgcn_exp2f((float)acc[m][n][1] * SC_EPI);
        rs2 += __builtin_amdgcn_exp2f((float)acc[m][n][2] * SC_EPI);
        rs3 += __builtin_amdgcn_exp2f((float)acc[m][n][3] * SC_EPI);
      }
      rs0 = row_sum16(rs0); rs1 = row_sum16(rs1);
      rs2 = row_sum16(rs2); rs3 = row_sum16(rs3);
      if (lr == 0) {
        int row = m * 16 + lk * 4;
        rw[row + 0] += rs0; rw[row + 1] += rs1;
        rw[row + 2] += rs2; rw[row + 3] += rs3;
      }
    }
  }

  // ---- final: combine 2 wc-waves per row, one coalesced store ----
  __syncthreads();
  if (t < 128) {
    int wr2 = t >> 6, r = t & 63;
    float sv = rsumAll[(wr2 * 2 + 0) * 64 + r] + rsumAll[(wr2 * 2 + 1) * 64 + r];
    partials[(size_t)(cg * 2 + sub) * N_ROWS + (size_t)br * 128 + t] = sv;
  }
}

// ---------------- per-row loss + block partial sums ----------------
__global__ __launch_bounds__(256) void k_loss1(const float* __restrict__ partials,
                                               const float* __restrict__ tgt,
                                               float* __restrict__ bsum) {
  __shared__ float wsum[4];
  int i = blockIdx.x * 256 + threadIdx.x;
  const float* p = partials + i;
  float s = -240.0f;   // remove padded cols 10000..10239 (acc=0 -> exp term 1.0)
#pragma unroll
  for (int j = 0; j < NCB; ++j) s += p[(size_t)j * N_ROWS];
  float tl = tgt[i];
  float tcv = fminf(fmaxf(tl, -1.0f + 1e-7f), 1.0f - 1e-7f);
  const float cm = 0.95533648912560601964f;   // cos(0.3)
  const float sm = 0.29552020666133957510f;   // sin(0.3)
  float num = S_SCALE * (tcv * cm - sqrtf(fmaxf(1.0f - tcv * tcv, 0.f)) * sm);
  float sum_excl = s - __expf(S_SCALE * tl);
  float denom = __expf(num) + sum_excl;
  float L = num - __logf(denom);
#pragma unroll
  for (int m = 1; m < 64; m <<= 1) L += __shfl_xor(L, m, 64);
  int l = threadIdx.x & 63, w = threadIdx.x >> 6;
  if (l == 0) wsum[w] = L;
  __syncthreads();
  if (threadIdx.x == 0) bsum[blockIdx.x] = wsum[0] + wsum[1] + wsum[2] + wsum[3];
}

__global__ void k_loss2(const float* __restrict__ bsum, float* __restrict__ out) {
  float s = 0.f;
  for (int i = 0; i < 32; ++i) s += bsum[i];
  out[0] = -s / (float)N_ROWS;
}

// ---------------- launch ----------------
extern "C" void kernel_launch(void* const* d_in, const int* in_sizes, int n_in,
                              void* d_out, int out_size, void* d_ws, size_t ws_size,
                              hipStream_t stream) {
  const float* x = (const float*)d_in[0];
  const float* W = (const float*)d_in[1];
  const int* target = (const int*)d_in[2];
  float* out = (float*)d_out;
  char* ws = (char*)d_ws;

  unsigned char* xnb8 = (unsigned char*)(ws);               // 64*32768     = 2,097,152
  unsigned char* WbF8 = (unsigned char*)(ws + 2097152);     // 640*4096     = 2,621,440
  float* tgt = (float*)(ws + 4718592);                      // 8192*4
  float* partials = (float*)(ws + 4751360);                 // 16*8192*4    = 524,288
  float* bsum = (float*)(ws + 5275648);                     // 32*4

  k_prep<<<3328, 256, 0, stream>>>(x, W, target, xnb8, WbF8, tgt);
  k_gemm<<<1024, 256, 0, stream>>>(xnb8, WbF8, partials);
  k_loss1<<<32, 256, 0, stream>>>(partials, tgt, bsum);
  k_loss2<<<1, 1, 0, stream>>>(bsum, out);
}

// Round 26
// 43.995 us; speedup vs baseline: 1.0403x; 1.0153x over previous
//
#include <hip/hip_runtime.h>
#include <hip/hip_bf16.h>
#include <stdint.h>

#define S_SCALE 30.0f
#define XSC 360.0f                 /* A int8 scale (max|xn| ~ 0.39 w/ clamp) */
#define WSC 400.0f                 /* W int8 scale (max|W| ~ 0.26) */
#define SC_EPI 3.00561467e-4f      /* 30*log2(e) / (360*400) */
#define N_ROWS 8192
#define D_DIM 256
#define C_CLS 10000
#define NCB 8

typedef __attribute__((ext_vector_type(4))) int i32x4;

static __device__ __forceinline__ void gl16(const void* g, void* l) {
  __builtin_amdgcn_global_load_lds(
      (const __attribute__((address_space(1))) void*)g,
      (__attribute__((address_space(3))) void*)l, 16, 0, 0);
}

// quantize 4 floats (pre-scaled) to packed int8x4, clamp +-127, round-nearest
static __device__ __forceinline__ int q4(float a, float b, float c, float d) {
  int qa = (int)rintf(fminf(fmaxf(a, -127.f), 127.f));
  int qb = (int)rintf(fminf(fmaxf(b, -127.f), 127.f));
  int qc = (int)rintf(fminf(fmaxf(c, -127.f), 127.f));
  int qd = (int)rintf(fminf(fmaxf(d, -127.f), 127.f));
  return (qa & 255) | ((qb & 255) << 8) | ((qc & 255) << 16) | ((qd & 255) << 24);
}

// 16-lane (DPP-row) sum, VALU pipe only; all lanes receive the group sum.
static __device__ __forceinline__ float row_sum16(float v) {
  union { float f; int i; } u, w;
  u.f = v;
  w.i = __builtin_amdgcn_update_dpp(0, u.i, 0xB1, 0xF, 0xF, true);  u.f += w.f; // lane^1
  w.i = __builtin_amdgcn_update_dpp(0, u.i, 0x4E, 0xF, 0xF, true);  u.f += w.f; // lane^2
  w.i = __builtin_amdgcn_update_dpp(0, u.i, 0x141, 0xF, 0xF, true); u.f += w.f; // half-mirror
  w.i = __builtin_amdgcn_update_dpp(0, u.i, 0x140, 0xF, 0xF, true); u.f += w.f; // row-mirror
  return u.f;
}

// ---- fused prep (int8): blocks <1280 convert W (x400) to 16x16x64 frag layout;
// rest L2-normalize x (x360) into A-frag layout + exact fp32 target logit.
// WbF8: [c16 0..639][kchunk 0..3][lane]16B; lane=lk*16+lr holds
// W[col=c16*16+lr][k=kchunk*64+lk*16 ..+16] as int8; cols >= C_CLS zero
// (acc contribution 0 -> exp2(0)=1, subtracted in k_loss1).
// xnb8: [panel 0..63] 32KB: slot (r16*4+kchunk)*1024 + flane*16 + byte;
// row = panel*128 + r16*16 + lr, flane = lk*16+lr, k = kchunk*64+lk*16+byte.
__global__ __launch_bounds__(256) void k_prep(const float* __restrict__ x,
                                              const float* __restrict__ W,
                                              const int* __restrict__ target,
                                              unsigned char* __restrict__ xnb8,
                                              unsigned char* __restrict__ WbF8,
                                              float* __restrict__ tgt) {
  if (blockIdx.x < 1280) {
    int gidx = blockIdx.x * 256 + threadIdx.x;   // 0..327679 = 640*4*64*2
    int sub = gidx & 1;                          // which 8B half of lane's 16B
    int lane = (gidx >> 1) & 63;
    int kchunk = (gidx >> 7) & 3;
    int c16 = gidx >> 9;
    int col = c16 * 16 + (lane & 15);
    int k0 = kchunk * 64 + (lane >> 4) * 16 + sub * 8;
    int r0 = 0, r1 = 0;
    if (col < C_CLS) {
      const float4 a = *(const float4*)(W + (size_t)col * D_DIM + k0);
      const float4 b = *(const float4*)(W + (size_t)col * D_DIM + k0 + 4);
      r0 = q4(a.x * WSC, a.y * WSC, a.z * WSC, a.w * WSC);
      r1 = q4(b.x * WSC, b.y * WSC, b.z * WSC, b.w * WSC);
    }
    size_t dst = (size_t)c16 * 4096 + (size_t)kchunk * 1024 +
                 (size_t)lane * 16 + (size_t)sub * 8;
    *(int2*)(WbF8 + dst) = (int2){r0, r1};
  } else {
    int row = (blockIdx.x - 1280) * 4 + (threadIdx.x >> 6);
    int l = threadIdx.x & 63;
    const float4 v = *(const float4*)(x + (size_t)row * D_DIM + l * 4);
    float ss = v.x * v.x + v.y * v.y + v.z * v.z + v.w * v.w;
#pragma unroll
    for (int m = 1; m < 64; m <<= 1) ss += __shfl_xor(ss, m, 64);
    float rn = 1.0f / sqrtf(ss);
    float s8 = rn * XSC;
    int r0 = q4(v.x * s8, v.y * s8, v.z * s8, v.w * s8);
    // this thread's 4 k-bytes: k0 = l*4
    int panel = row >> 7, r16 = (row >> 4) & 7, lr = row & 15;
    int kchunk = l >> 4;
    int lk = (l >> 2) & 3;
    int byte = (l & 3) * 4;
    size_t dst = (size_t)panel * 32768 + (size_t)(r16 * 4 + kchunk) * 1024 +
                 (size_t)(lk * 16 + lr) * 16 + byte;
    *(int*)(xnb8 + dst) = r0;
    // exact fp32 target logit
    int tc = target[row];
    const float4 b = *(const float4*)(W + (size_t)tc * D_DIM + l * 4);
    float s = v.x * b.x + v.y * b.y + v.z * b.z + v.w * b.w;
#pragma unroll
    for (int m = 1; m < 64; m <<= 1) s += __shfl_xor(s, m, 64);
    if (l == 0) tgt[row] = s * rn;
  }
}

// ------- barrier-free fused i8 GEMM (16x16x64, 2x fp8 rate) + exp-sum -------
// Converged best (r23): 512 blocks 2/CU, 8 waves 2Mx4N, wave 64x64, A panel
// 32 KB staged once, 5 col-tiles. mfma_i32_16x16x64_i8 (K=64; int32 acc EXACT;
// quant err ~3e-3/logit -> ~1e-3 on loss). Frags 16B/lane single-tuple loads.
// Registers: acc 64 AGPR + B single-buffer 16 VGPR + A 4 + addr ~ 120 <= 128
// cap -- the never-spilled config. B latency hidden by 4-wave/SIMD TLP +
// epilogue overlap. Folded exp scale (epilogue = cvt+mul+exp2), zero-free
// first window, no padding mask (-240 const in k_loss1).
__global__ __launch_bounds__(512, 4) void k_gemm(const unsigned char* __restrict__ xnb8,
                                                 const unsigned char* __restrict__ WbF8,
                                                 float* __restrict__ partials) {
  __shared__ __align__(16) char lds[34816];   // A frags 32 KB @0; rsum 2 KB @32768
  const int b = blockIdx.x;
  const int cg = b & 7;                              // XCD colgroup 0..7
  const int br = b >> 3;                             // row panel 0..63 (128 rows)
  const int bc0 = cg * 5;                            // 5 consecutive 256-col tiles
  const int t = threadIdx.x;
  const int w = t >> 6, l = t & 63;
  const int wr = w >> 2, wc = w & 3;                 // 2M x 4N waves (64x64 tile)
  const int lr = l & 15, lk = l >> 4;
  float* rsumAll = (float*)(lds + 32768);            // [8 waves][64 rows]

  if (t < 512) rsumAll[t] = 0.f;                     // covered by staging barrier

  // ---- stage A panel once: pure linear 32 KB copy into frag-order LDS ----
  {
    const char* Ag = (const char*)xnb8 + (size_t)br * 32768;
#pragma unroll
    for (int i = 0; i < 4; ++i)
      gl16(Ag + i * 8192 + w * 1024 + l * 16, lds + i * 8192 + w * 1024);
    asm volatile("s_waitcnt vmcnt(0)" ::: "memory");
    __builtin_amdgcn_sched_barrier(0);
    __builtin_amdgcn_s_barrier();
  }

  i32x4 acc[4][4];
  const i32x4 zi = (i32x4){0, 0, 0, 0};

  // wave's A base in LDS (slot = (wr*4+fm)*4 + kc, 1024 B each), per-lane 16B
  const char* AwL = lds + (size_t)wr * 16384 + (size_t)l * 16;
  // wave's B base in global frag layout (c16 = bc*16 + wc*4 + fn), per-lane 16B
  const unsigned char* Bw = WbF8 + (size_t)(bc0 * 16 + wc * 4) * 4096 + (size_t)l * 16;
  float* rw = rsumAll + w * 64;                      // this wave's private rows

  for (int tt = 0; tt < 5; ++tt) {
    const unsigned char* Bt = Bw + (size_t)tt * 65536;  // 16 c16 * 4096 per tile

    auto windw = [&](int kc, bool first) {
      i32x4 bf[4];
#pragma unroll
      for (int fn = 0; fn < 4; ++fn)
        bf[fn] = *(const i32x4*)(Bt + fn * 4096 + kc * 1024);
      __builtin_amdgcn_s_setprio(1);
#pragma unroll
      for (int fm = 0; fm < 4; ++fm) {
        i32x4 a = *(const i32x4*)(AwL + (fm * 4 + kc) * 1024);
#pragma unroll
        for (int fn = 0; fn < 4; ++fn)
          acc[fm][fn] = __builtin_amdgcn_mfma_i32_16x16x64_i8(
              a, bf[fn], first ? zi : acc[fm][fn], 0, 0, 0);
      }
      __builtin_amdgcn_s_setprio(0);
    };
    windw(0, true); windw(1, false); windw(2, false); windw(3, false);

    // ---- per-tile epilogue: cvt+scale+exp2, DPP col-reduce, LDS rows ----
    // 16x16 C/D: col = lane&15, row = (lane>>4)*4 + j. No mask: padded cols
    // give acc=0 -> exp2(0)=1, removed as a constant in k_loss1.
#pragma unroll
    for (int m = 0; m < 4; ++m) {
      float rs0 = 0.f, rs1 = 0.f, rs2 = 0.f, rs3 = 0.f;
#pragma unroll
      for (int n = 0; n < 4; ++n) {
        rs0 += __builtin_amdgcn_exp2f((float)acc[m][n][0] * SC_EPI);
        rs1 += __builtin_amdgcn_exp2f((float)acc[m][n][1] * SC_EPI);
        rs2 += __builtin_amdgcn_exp2f((float)acc[m][n][2] * SC_EPI);
        rs3 += __builtin_amdgcn_exp2f((float)acc[m][n][3] * SC_EPI);
      }
      rs0 = row_sum16(rs0); rs1 = row_sum16(rs1);
      rs2 = row_sum16(rs2); rs3 = row_sum16(rs3);
      if (lr == 0) {
        int row = m * 16 + lk * 4;
        rw[row + 0] += rs0; rw[row + 1] += rs1;
        rw[row + 2] += rs2; rw[row + 3] += rs3;
      }
    }
  }

  // ---- final: combine 4 wc-waves per row, one coalesced store ----
  __syncthreads();
  if (t < 128) {
    int wr2 = t >> 6, r = t & 63;
    float sv = rsumAll[(wr2 * 4 + 0) * 64 + r] + rsumAll[(wr2 * 4 + 1) * 64 + r] +
               rsumAll[(wr2 * 4 + 2) * 64 + r] + rsumAll[(wr2 * 4 + 3) * 64 + r];
    partials[(size_t)cg * N_ROWS + (size_t)br * 128 + t] = sv;
  }
}

// ---------------- per-row loss + block partial sums ----------------
__global__ __launch_bounds__(256) void k_loss1(const float* __restrict__ partials,
                                               const float* __restrict__ tgt,
                                               float* __restrict__ bsum) {
  __shared__ float wsum[4];
  int i = blockIdx.x * 256 + threadIdx.x;
  const float* p = partials + i;
  float s = -240.0f;   // remove padded cols 10000..10239 (acc=0 -> exp term 1.0)
#pragma unroll
  for (int j = 0; j < NCB; ++j) s += p[(size_t)j * N_ROWS];
  float tl = tgt[i];
  float tcv = fminf(fmaxf(tl, -1.0f + 1e-7f), 1.0f - 1e-7f);
  const float cm = 0.95533648912560601964f;   // cos(0.3)
  const float sm = 0.29552020666133957510f;   // sin(0.3)
  float num = S_SCALE * (tcv * cm - sqrtf(fmaxf(1.0f - tcv * tcv, 0.f)) * sm);
  float sum_excl = s - __expf(S_SCALE * tl);
  float denom = __expf(num) + sum_excl;
  float L = num - __logf(denom);
#pragma unroll
  for (int m = 1; m < 64; m <<= 1) L += __shfl_xor(L, m, 64);
  int l = threadIdx.x & 63, w = threadIdx.x >> 6;
  if (l == 0) wsum[w] = L;
  __syncthreads();
  if (threadIdx.x == 0) bsum[blockIdx.x] = wsum[0] + wsum[1] + wsum[2] + wsum[3];
}

__global__ void k_loss2(const float* __restrict__ bsum, float* __restrict__ out) {
  float s = 0.f;
  for (int i = 0; i < 32; ++i) s += bsum[i];
  out[0] = -s / (float)N_ROWS;
}

// ---------------- launch ----------------
extern "C" void kernel_launch(void* const* d_in, const int* in_sizes, int n_in,
                              void* d_out, int out_size, void* d_ws, size_t ws_size,
                              hipStream_t stream) {
  const float* x = (const float*)d_in[0];
  const float* W = (const float*)d_in[1];
  const int* target = (const int*)d_in[2];
  float* out = (float*)d_out;
  char* ws = (char*)d_ws;

  unsigned char* xnb8 = (unsigned char*)(ws);               // 64*32768     = 2,097,152
  unsigned char* WbF8 = (unsigned char*)(ws + 2097152);     // 640*4096     = 2,621,440
  float* tgt = (float*)(ws + 4718592);                      // 8192*4
  float* partials = (float*)(ws + 4751360);                 // 8*8192*4     = 262,144
  float* bsum = (float*)(ws + 5013504);                     // 32*4

  k_prep<<<3328, 256, 0, stream>>>(x, W, target, xnb8, WbF8, tgt);
  k_gemm<<<512, 512, 0, stream>>>(xnb8, WbF8, partials);
  k_loss1<<<32, 256, 0, stream>>>(partials, tgt, bsum);
  k_loss2<<<1, 1, 0, stream>>>(bsum, out);
}